// Round 1
// baseline (10345.632 us; speedup 1.0000x reference)
//
#include <hip/hip_runtime.h>
#include <hip/hip_bf16.h>

typedef float f32x4 __attribute__((ext_vector_type(4)));
typedef short short8 __attribute__((ext_vector_type(8)));

#define B_ 8
#define S_ 1024
#define V_ 32000
#define E_ 256
#define H_ 512

// workspace layout (bytes)
#define OFF_CNT    0ul
#define OFF_HBF    256ul                       // h bf16 [16][512]   = 16384 B
#define OFF_RHBF   (OFF_HBF + 16384ul)         // r*h bf16 [16][512] = 16384 B
#define OFF_WHH    (OFF_RHBF + 16384ul)        // 32 WGs * 24576 bf16 = 1572864 B
#define OFF_WOF    (OFF_WHH + 1572864ul)       // Wo fragments: 16384000 bf16 = 32768000 B
#define OFF_HSBF   (OFF_WOF + 32768000ul)      // hs bf16 [8192][512] = 8388608 B
#define OFF_XPROJ  (OFF_HSBF + 8388608ul)      // xproj f32 [1024][1536][8] = 50331648 B
// total = 93,094,144 B

__device__ __forceinline__ unsigned short f2bf(float f) {
    unsigned u = __float_as_uint(f);
    unsigned r = (u + 0x7fffu + ((u >> 16) & 1u)) >> 16;
    return (unsigned short)r;
}
__device__ __forceinline__ float sigmoidf_(float x) { return 1.0f / (1.0f + __expf(-x)); }
__device__ __forceinline__ float tanhf_(float x) {
    float e = __expf(2.0f * x);
    return (e - 1.0f) / (e + 1.0f);
}

// ---------------------------------------------------------------------------
// init: convert Wo into MFMA-B fragment layout (bf16), convert recurrence
// weights into per-WG LDS fragment images, zero h/rh state + barrier counter.
// ---------------------------------------------------------------------------
__global__ void __launch_bounds__(256) init_kernel(char* ws, const float* Wr, const float* Wz,
                                                   const float* Wc, const float* Wo) {
    unsigned gid = blockIdx.x * 256u + threadIdx.x;
    unsigned stride = gridDim.x * 256u;

    // Wo fragments: element (vt,kc,lane,j) = Wo[k][col], k=kc*32+(lane>>4)*8+j, col=vt*16+(lane&15)
    unsigned short* wof = (unsigned short*)(ws + OFF_WOF);
    for (unsigned i = gid; i < 16384000u; i += stride) {
        unsigned vt = i >> 13, rem = i & 8191u;
        unsigned kc = rem >> 9, l = (rem >> 3) & 63u, j = i & 7u;
        unsigned k = kc * 32u + (l >> 4) * 8u + j;
        unsigned col = vt * 16u + (l & 15u);
        wof[i] = f2bf(Wo[k * 32000u + col]);
    }

    // W_h fragments per recurrence WG g: tiles {r,z,c}, cols [16g,16g+16)
    unsigned short* whh = (unsigned short*)(ws + OFF_WHH);
    for (unsigned i = gid; i < 786432u; i += stride) {
        unsigned g = i / 24576u, rem = i % 24576u;
        unsigned tile = rem / 8192u, rem2 = rem & 8191u;
        unsigned kk = rem2 >> 9, l = (rem2 >> 3) & 63u, j = i & 7u;
        unsigned k = kk * 32u + (l >> 4) * 8u + j;      // k in [0,512) = h-rows of W
        unsigned col = g * 16u + (l & 15u);
        const float* Wg = (tile == 0) ? Wr : (tile == 1) ? Wz : Wc;
        whh[i] = f2bf(Wg[k * 512u + col]);
    }

    // zero h_bf + rh_bf (incl. padding rows 8..15) ; zero barrier counter
    float* zr = (float*)(ws + OFF_HBF);
    for (unsigned i = gid; i < 8192u; i += stride) zr[i] = 0.f;
    if (gid == 0) *(unsigned*)(ws + OFF_CNT) = 0u;
}

// ---------------------------------------------------------------------------
// xproj: xproj[t][col][b] = bias[col] + sum_e embed[tok(t,b)][e]*W[512+e][col]
// col in [0,1536): 0-511 r, 512-1023 z, 1024-1535 c. Block handles 2 timesteps.
// ---------------------------------------------------------------------------
__global__ void __launch_bounds__(256) xproj_kernel(char* ws, const int* tokens, const float* embed,
                                                    const float* Wr, const float* br,
                                                    const float* Wz, const float* bz,
                                                    const float* Wc, const float* bc) {
    __shared__ float xT[256 * 2 * 8];  // [e][tt][b]
    const int tid = threadIdx.x;
    const int t0 = blockIdx.x * 2;

    for (int p = 0; p < 16; ++p) {
        int tt = p >> 3, b = p & 7;
        int tok = tokens[b * 1024 + t0 + tt];
        xT[tid * 16 + tt * 8 + b] = embed[tok * 256 + tid];
    }
    __syncthreads();

    float* xp = (float*)(ws + OFF_XPROJ);
    for (int cc = 0; cc < 6; ++cc) {
        const int gate = cc >> 1;
        const int jg = (cc & 1) * 256 + tid;
        const float* Wg = gate == 0 ? Wr : gate == 1 ? Wz : Wc;
        const float* bg = gate == 0 ? br : gate == 1 ? bz : bc;
        const float* wp = Wg + 512 * 512 + jg;  // x-part rows, column jg
        const float bias = bg[jg];
        f32x4 a00 = {bias, bias, bias, bias}, a01 = a00, a10 = a00, a11 = a00;
        for (int e = 0; e < 256; ++e) {
            float w = wp[e * 512];
            f32x4 x00 = *(const f32x4*)&xT[e * 16 + 0];
            f32x4 x01 = *(const f32x4*)&xT[e * 16 + 4];
            f32x4 x10 = *(const f32x4*)&xT[e * 16 + 8];
            f32x4 x11 = *(const f32x4*)&xT[e * 16 + 12];
            a00 += w * x00; a01 += w * x01; a10 += w * x10; a11 += w * x11;
        }
        const int j = cc * 256 + tid;  // global col in [0,1536)
        float* d0 = xp + ((size_t)(t0 + 0) * 1536 + j) * 8;
        float* d1 = xp + ((size_t)(t0 + 1) * 1536 + j) * 8;
        *(f32x4*)(d0 + 0) = a00; *(f32x4*)(d0 + 4) = a01;
        *(f32x4*)(d1 + 0) = a10; *(f32x4*)(d1 + 4) = a11;
    }
}

// ---------------------------------------------------------------------------
// recurrence: 32 persistent WGs x 256 threads. WG g owns columns [16g,16g+16)
// of r, z, c, h. Weights LDS-stationary as MFMA B-fragments. 2 barriers/step.
// ---------------------------------------------------------------------------
__global__ void __launch_bounds__(256) rec_kernel(char* ws) {
    __shared__ short lw[24576];      // 3 tiles * 16 kk * 64 lanes * 8 bf16
    __shared__ float redbuf[768];    // K-split partial sums
    __shared__ float h_loc[128];     // [col16][b] fp32, this WG's h columns
    __shared__ float z_loc[128];     // [col16][b]

    const int tid = threadIdx.x;
    const int g = blockIdx.x;
    const int wave = tid >> 6, lane = tid & 63;
    const int q = lane >> 4, cn = lane & 15;

    unsigned short* hbf  = (unsigned short*)(ws + OFF_HBF);
    unsigned short* rhbf = (unsigned short*)(ws + OFF_RHBF);
    unsigned short* hsbf = (unsigned short*)(ws + OFF_HSBF);
    const float* xp = (const float*)(ws + OFF_XPROJ);
    unsigned* cnt = (unsigned*)(ws + OFF_CNT);

    {   // stage this WG's weight fragments into LDS
        const f32x4* src = (const f32x4*)(ws + OFF_WHH + (size_t)g * 49152u);
        f32x4* dst = (f32x4*)lw;
        for (int i = tid; i < 3072; i += 256) dst[i] = src[i];
    }
    if (tid < 128) { h_loc[tid] = 0.f; z_loc[tid] = 0.f; }
    __syncthreads();

    const int jcol = g * 16 + cn;                 // owned column (epilogue lanes)
    const int abyte = (lane & 15) * 1024 + q * 16; // A-frag byte base (+kk*64)
    const short8* bsrc1 = ((const short8*)lw) + (wave & 1) * 1024 + lane;
    const short8* bsrc2 = ((const short8*)lw) + 2048 + lane;

    #pragma unroll 1
    for (int t = 0; t < 1024; ++t) {
        // prefetch xproj for this step (hidden under MFMA + barrier)
        f32x4 xr4 = {0,0,0,0}, xz4 = {0,0,0,0}, xc4 = {0,0,0,0};
        if (q < 2) {
            const float* xpt = xp + (size_t)t * 12288;
            if (wave == 0) {
                xr4 = *(const f32x4*)(xpt + (size_t)jcol * 8 + q * 4);
                xc4 = *(const f32x4*)(xpt + (size_t)(1024 + jcol) * 8 + q * 4);
            } else if (wave == 1) {
                xz4 = *(const f32x4*)(xpt + (size_t)(512 + jcol) * 8 + q * 4);
            }
        }

        // ---- phase 1: pre_r (tile0) and pre_z (tile1) = h @ W ----
        const int tile = wave & 1;
        const int kk0 = (wave >> 1) * 8;
        f32x4 acc = {0.f, 0.f, 0.f, 0.f};
        #pragma unroll
        for (int kki = 0; kki < 8; ++kki) {
            int kk = kk0 + kki;
            short8 a = *(const short8*)((const char*)hbf + (abyte + kk * 64));
            short8 b = bsrc1[kk * 64];
            acc = __builtin_amdgcn_mfma_f32_16x16x32_bf16(a, b, acc, 0, 0, 0);
        }
        if (wave >= 2) {
            #pragma unroll
            for (int r = 0; r < 4; ++r) redbuf[tile * 256 + (q * 4 + r) * 16 + cn] = acc[r];
        }
        __syncthreads();
        if (wave < 2) {
            #pragma unroll
            for (int r = 0; r < 4; ++r) acc[r] += redbuf[tile * 256 + (q * 4 + r) * 16 + cn];
            if (q < 2) {
                if (tile == 0) {  // r gate -> write r*h (bf16, global all-gather)
                    #pragma unroll
                    for (int r = 0; r < 4; ++r) {
                        float rv = sigmoidf_(acc[r] + xr4[r]);
                        float rh = rv * h_loc[cn * 8 + q * 4 + r];
                        rhbf[(q * 4 + r) * 512 + jcol] = f2bf(rh);
                    }
                } else {          // z gate -> WG-local LDS
                    #pragma unroll
                    for (int r = 0; r < 4; ++r)
                        z_loc[cn * 8 + q * 4 + r] = sigmoidf_(acc[r] + xz4[r]);
                }
            }
        }
        __syncthreads();
        if (tid == 0) {
            __threadfence();
            __hip_atomic_fetch_add(cnt, 1u, __ATOMIC_RELAXED, __HIP_MEMORY_SCOPE_AGENT);
            unsigned target = 32u * (2u * (unsigned)t + 1u);
            while (__hip_atomic_load(cnt, __ATOMIC_RELAXED, __HIP_MEMORY_SCOPE_AGENT) < target)
                __builtin_amdgcn_s_sleep(1);
            __threadfence();
        }
        __syncthreads();

        // ---- phase 2: pre_c = (r*h) @ Wc ; h_new = (1-z)*c + z*h ----
        f32x4 acc2 = {0.f, 0.f, 0.f, 0.f};
        #pragma unroll
        for (int i = 0; i < 4; ++i) {
            int kk = wave * 4 + i;
            short8 a = *(const short8*)((const char*)rhbf + (abyte + kk * 64));
            short8 b = bsrc2[kk * 64];
            acc2 = __builtin_amdgcn_mfma_f32_16x16x32_bf16(a, b, acc2, 0, 0, 0);
        }
        if (wave >= 1) {
            #pragma unroll
            for (int r = 0; r < 4; ++r) redbuf[(wave - 1) * 256 + (q * 4 + r) * 16 + cn] = acc2[r];
        }
        __syncthreads();
        if (wave == 0) {
            #pragma unroll
            for (int r = 0; r < 4; ++r) {
                float pre = acc2[r] + redbuf[(q * 4 + r) * 16 + cn]
                                    + redbuf[256 + (q * 4 + r) * 16 + cn]
                                    + redbuf[512 + (q * 4 + r) * 16 + cn];
                if (q < 2) {
                    float c = tanhf_(pre + xc4[r]);
                    float z = z_loc[cn * 8 + q * 4 + r];
                    float hold = h_loc[cn * 8 + q * 4 + r];
                    float hnew = (1.f - z) * c + z * hold;
                    h_loc[cn * 8 + q * 4 + r] = hnew;
                    unsigned short hb = f2bf(hnew);
                    int b = q * 4 + r;
                    hbf[b * 512 + jcol] = hb;
                    hsbf[((size_t)(t * 8 + b)) * 512 + jcol] = hb;
                }
            }
        }
        __syncthreads();
        if (tid == 0) {
            __threadfence();
            __hip_atomic_fetch_add(cnt, 1u, __ATOMIC_RELAXED, __HIP_MEMORY_SCOPE_AGENT);
            unsigned target = 32u * (2u * (unsigned)t + 2u);
            while (__hip_atomic_load(cnt, __ATOMIC_RELAXED, __HIP_MEMORY_SCOPE_AGENT) < target)
                __builtin_amdgcn_s_sleep(1);
            __threadfence();
        }
        __syncthreads();
    }
}

// ---------------------------------------------------------------------------
// logits: out[b][t][v] = hs[t,b] @ Wo + bo. 128x128 tiles, bf16 MFMA.
// ---------------------------------------------------------------------------
__global__ void __launch_bounds__(256) gemm_kernel(const char* ws, const float* bo, float* out) {
    const int blk = blockIdx.x;
    const int mt = blk / 250, nt = blk % 250;
    const int tid = threadIdx.x;
    const int wave = tid >> 6, lane = tid & 63;
    const int q = lane >> 4, cn = lane & 15;
    const int wm = wave >> 1, wn = wave & 1;

    const unsigned short* hsbf = (const unsigned short*)(ws + OFF_HSBF);
    const unsigned short* wof  = (const unsigned short*)(ws + OFF_WOF);

    const int rbase = mt * 128 + wm * 64;
    const int vbase = nt * 128 + wn * 64;
    const int vt0 = vbase >> 4;

    f32x4 acc[4][4];
    #pragma unroll
    for (int mi = 0; mi < 4; ++mi)
        #pragma unroll
        for (int ni = 0; ni < 4; ++ni) acc[mi][ni] = (f32x4){0, 0, 0, 0};

    const char* abase = (const char*)hsbf + (size_t)(rbase + cn) * 1024 + q * 16;
    const char* bbase = (const char*)wof + ((size_t)vt0 * 8192 + (size_t)lane * 8) * 2;

    for (int kc = 0; kc < 16; ++kc) {
        short8 a[4], b[4];
        #pragma unroll
        for (int mi = 0; mi < 4; ++mi)
            a[mi] = *(const short8*)(abase + (size_t)mi * 16 * 1024 + kc * 64);
        #pragma unroll
        for (int ni = 0; ni < 4; ++ni)
            b[ni] = *(const short8*)(bbase + ((size_t)ni * 8192 + kc * 512) * 2);
        #pragma unroll
        for (int mi = 0; mi < 4; ++mi)
            #pragma unroll
            for (int ni = 0; ni < 4; ++ni)
                acc[mi][ni] = __builtin_amdgcn_mfma_f32_16x16x32_bf16(a[mi], b[ni], acc[mi][ni], 0, 0, 0);
    }

    #pragma unroll
    for (int ni = 0; ni < 4; ++ni) {
        const int v = vbase + ni * 16 + cn;
        const float bias = bo[v];
        #pragma unroll
        for (int mi = 0; mi < 4; ++mi) {
            const int row0 = rbase + mi * 16 + q * 4;
            #pragma unroll
            for (int r = 0; r < 4; ++r) {
                const int row = row0 + r;          // row = t*8 + b
                const int tt = row >> 3, b = row & 7;
                out[(size_t)b * 32768000u + (size_t)tt * 32000u + v] = acc[mi][ni][r] + bias;
            }
        }
    }
}

extern "C" void kernel_launch(void* const* d_in, const int* in_sizes, int n_in,
                              void* d_out, int out_size, void* d_ws, size_t ws_size,
                              hipStream_t stream) {
    const int*   tokens = (const int*)d_in[0];
    const float* embed  = (const float*)d_in[1];
    const float* Wr     = (const float*)d_in[2];
    const float* br     = (const float*)d_in[3];
    const float* Wz     = (const float*)d_in[4];
    const float* bz     = (const float*)d_in[5];
    const float* Wc     = (const float*)d_in[6];
    const float* bc     = (const float*)d_in[7];
    const float* Wo     = (const float*)d_in[8];
    const float* bo     = (const float*)d_in[9];
    float* out = (float*)d_out;
    char* ws = (char*)d_ws;

    hipLaunchKernelGGL(init_kernel, dim3(4096), dim3(256), 0, stream, ws, Wr, Wz, Wc, Wo);
    hipLaunchKernelGGL(xproj_kernel, dim3(512), dim3(256), 0, stream,
                       ws, tokens, embed, Wr, br, Wz, bz, Wc, bc);
    hipLaunchKernelGGL(rec_kernel, dim3(32), dim3(256), 0, stream, ws);
    hipLaunchKernelGGL(gemm_kernel, dim3(16000), dim3(256), 0, stream, ws, bo, out);
}